// Round 1
// baseline (1434.338 us; speedup 1.0000x reference)
//
#include <hip/hip_runtime.h>
#include <cstdint>
#include <cstddef>

// ---------------- CSR construction ----------------

__global__ void deg_kernel(const int* __restrict__ edst, int* __restrict__ deg, int E) {
  int i = blockIdx.x * 256 + threadIdx.x;
  if (i < E) atomicAdd(&deg[edst[i]], 1);
}

__global__ void chunk_sum_kernel(const int* __restrict__ deg, int* __restrict__ csum, int n) {
  __shared__ int wsum[16];
  int t = threadIdx.x;
  int i = blockIdx.x * 1024 + t;
  int v = (i < n) ? deg[i] : 0;
  for (int m = 1; m < 64; m <<= 1) v += __shfl_xor(v, m);
  if ((t & 63) == 0) wsum[t >> 6] = v;
  __syncthreads();
  if (t == 0) {
    int s = 0;
    for (int j = 0; j < 16; ++j) s += wsum[j];
    csum[blockIdx.x] = s;
  }
}

// single block: inclusive scan of chunk sums (nchunks <= 1024)
__global__ void scan_chunks_kernel(int* __restrict__ csum, int nchunks) {
  __shared__ int wsum[16];
  int t = threadIdx.x;
  int lane = t & 63, w = t >> 6;
  int x = (t < nchunks) ? csum[t] : 0;
  for (int off = 1; off < 64; off <<= 1) { int y = __shfl_up(x, off); if (lane >= off) x += y; }
  if (lane == 63) wsum[w] = x;
  __syncthreads();
  if (t < 16) {
    int s = wsum[t];
    for (int off = 1; off < 16; off <<= 1) { int y = __shfl_up(s, off); if (t >= off) s += y; }
    wsum[t] = s;
  }
  __syncthreads();
  if (w > 0) x += wsum[w - 1];
  if (t < nchunks) csum[t] = x;
}

__global__ void scan_final_kernel(const int* __restrict__ deg, const int* __restrict__ csum,
                                  int* __restrict__ rowptr, int n) {
  __shared__ int wsum[16];
  int t = threadIdx.x, b = blockIdx.x;
  int i = b * 1024 + t;
  int lane = t & 63, w = t >> 6;
  int x = (i < n) ? deg[i] : 0;
  for (int off = 1; off < 64; off <<= 1) { int y = __shfl_up(x, off); if (lane >= off) x += y; }
  if (lane == 63) wsum[w] = x;
  __syncthreads();
  if (t < 16) {
    int s = wsum[t];
    for (int off = 1; off < 16; off <<= 1) { int y = __shfl_up(s, off); if (t >= off) s += y; }
    wsum[t] = s;
  }
  __syncthreads();
  if (w > 0) x += wsum[w - 1];
  int off0 = (b > 0) ? csum[b - 1] : 0;
  if (i < n) rowptr[i + 1] = off0 + x;
  if (b == 0 && t == 0) rowptr[0] = 0;
}

__global__ void fill_kernel(const int* __restrict__ esrc, const int* __restrict__ edst,
                            const int* __restrict__ rowptr, int* __restrict__ fillc,
                            int* __restrict__ csr_src, int E) {
  int i = blockIdx.x * 256 + threadIdx.x;
  if (i < E) {
    int d = edst[i];
    int pos = atomicAdd(&fillc[d], 1);
    csr_src[rowptr[d] + pos] = esrc[i];
  }
}

// ---------------- GEMM1: h1 = x @ W1  (N x 128 @ 128 x 128) ----------------
// block 256 threads, 64 rows/block. W1 staged in LDS; x rows via L1 broadcasts.
__global__ void gemm1_kernel(const float* __restrict__ x, const float* __restrict__ W,
                             float* __restrict__ h1, int n) {
  __shared__ float wlds[128 * 128];
  int t = threadIdx.x;
  for (int i = t * 4; i < 128 * 128; i += 256 * 4)
    *(float4*)&wlds[i] = *(const float4*)&W[i];
  __syncthreads();
  int cg = t & 31, rg = t >> 5;   // 32 col groups x 8 row groups
  int c0 = cg * 4;
  int row0 = blockIdx.x * 64 + rg * 8;
  float acc[8][4] = {};
  const float* xr[8];
  #pragma unroll
  for (int i = 0; i < 8; ++i) {
    int r = row0 + i;
    xr[i] = x + (size_t)(r < n ? r : 0) * 128;
  }
  #pragma unroll 4
  for (int k = 0; k < 128; ++k) {
    float4 w4 = *(float4*)&wlds[k * 128 + c0];
    #pragma unroll
    for (int i = 0; i < 8; ++i) {
      float xv = xr[i][k];
      acc[i][0] += xv * w4.x; acc[i][1] += xv * w4.y;
      acc[i][2] += xv * w4.z; acc[i][3] += xv * w4.w;
    }
  }
  #pragma unroll
  for (int i = 0; i < 8; ++i) {
    int r = row0 + i;
    if (r < n) {
      float4 o = { acc[i][0], acc[i][1], acc[i][2], acc[i][3] };
      *(float4*)&h1[(size_t)r * 128 + c0] = o;
    }
  }
}

// ---------------- attention coefficients layer 1: a_s[n,h], a_d[n,h] ----------------
// one wave per node; lane reads channels lane and lane+64; reduce per 16-lane group.
__global__ void att1_kernel(const float* __restrict__ h1, const float* __restrict__ asw,
                            const float* __restrict__ adw,
                            float* __restrict__ a_s, float* __restrict__ a_d, int n) {
  int node = blockIdx.x * 4 + (threadIdx.x >> 6);
  int lane = threadIdx.x & 63;
  if (node >= n) return;
  float v1 = h1[(size_t)node * 128 + lane];
  float v2 = h1[(size_t)node * 128 + 64 + lane];
  float ps1 = v1 * asw[lane],      pd1 = v1 * adw[lane];
  float ps2 = v2 * asw[64 + lane], pd2 = v2 * adw[64 + lane];
  #pragma unroll
  for (int m = 1; m < 16; m <<= 1) {
    ps1 += __shfl_xor(ps1, m); pd1 += __shfl_xor(pd1, m);
    ps2 += __shfl_xor(ps2, m); pd2 += __shfl_xor(pd2, m);
  }
  if ((lane & 15) == 0) {
    int h = lane >> 4;
    a_s[(size_t)node * 8 + h]     = ps1;
    a_s[(size_t)node * 8 + 4 + h] = ps2;
    a_d[(size_t)node * 8 + h]     = pd1;
    a_d[(size_t)node * 8 + 4 + h] = pd2;
  }
}

// ---------------- GAT layer 1 aggregate: per-dst online softmax + weighted sum ----------------
// block = 128 threads (thread t owns output channel t); chunked over in-edges.
__global__ void gat1_agg_kernel(const int* __restrict__ rowptr, const int* __restrict__ csr_src,
                                const float* __restrict__ h1,
                                const float* __restrict__ a_s, const float* __restrict__ a_d,
                                const float* __restrict__ b1, float* __restrict__ hmid, int n) {
  int dst = blockIdx.x;
  int t = threadIdx.x;
  int beg = rowptr[dst], end = rowptr[dst + 1];
  int deg = end - beg;

  __shared__ float e_lds[128][8];
  __shared__ int   src_lds[128];
  __shared__ float M[8], S[8], scale[8];
  if (t < 8) { M[t] = -1e30f; S[t] = 0.f; }

  float ad[8];
  #pragma unroll
  for (int h = 0; h < 8; ++h) ad[h] = a_d[(size_t)dst * 8 + h];

  float acc = 0.f;
  int hh = t >> 4;

  for (int base = 0; base < deg; base += 128) {
    int cnt = min(128, deg - base);
    if (t < cnt) {
      int s = csr_src[beg + base + t];
      src_lds[t] = s;
      const float4* ap = (const float4*)&a_s[(size_t)s * 8];
      float4 A0 = ap[0], A1 = ap[1];
      float ev[8] = { A0.x + ad[0], A0.y + ad[1], A0.z + ad[2], A0.w + ad[3],
                      A1.x + ad[4], A1.y + ad[5], A1.z + ad[6], A1.w + ad[7] };
      #pragma unroll
      for (int h = 0; h < 8; ++h) {
        float e = ev[h];
        e_lds[t][h] = e > 0.f ? e : 0.2f * e;
      }
    }
    __syncthreads();
    if (t < 8) {
      int h = t;
      float m = M[h], cm = m;
      for (int i = 0; i < cnt; ++i) cm = fmaxf(cm, e_lds[i][h]);
      float sc = __expf(m - cm);
      float s = S[h] * sc;
      for (int i = 0; i < cnt; ++i) { float p = __expf(e_lds[i][h] - cm); e_lds[i][h] = p; s += p; }
      M[h] = cm; S[h] = s; scale[h] = sc;
    }
    __syncthreads();
    acc *= scale[hh];
    for (int i = 0; i < cnt; ++i)
      acc += e_lds[i][hh] * h1[(size_t)src_lds[i] * 128 + t];
    __syncthreads();
  }

  float denom = S[hh] + 1e-16f;
  float v = acc / denom + b1[t];
  v = v > 0.f ? v : (__expf(v) - 1.f);   // ELU
  hmid[(size_t)dst * 128 + t] = v;
}

// ---------------- GEMM2 + att2 fused: h2 = hmid @ W2; a_s2/a_d2 dots ----------------
__global__ void gemm2_att2_kernel(const float* __restrict__ hmid, const float* __restrict__ W2,
                                  const float* __restrict__ asw, const float* __restrict__ adw,
                                  float* __restrict__ h2, float* __restrict__ a_s2,
                                  float* __restrict__ a_d2, int n) {
  __shared__ float w[128 * 16];
  int t = threadIdx.x;
  for (int i = t; i < 128 * 16; i += 256) w[i] = W2[i];
  __syncthreads();
  int gid = blockIdx.x * 256 + t;
  int node = gid >> 4, c = gid & 15;
  if (node >= n) return;
  const float* row = &hmid[(size_t)node * 128];
  float acc = 0.f;
  #pragma unroll 4
  for (int k = 0; k < 128; ++k) acc += row[k] * w[k * 16 + c];
  h2[(size_t)node * 16 + c] = acc;
  float ps = acc * asw[c], pd = acc * adw[c];
  #pragma unroll
  for (int m = 1; m < 16; m <<= 1) { ps += __shfl_xor(ps, m); pd += __shfl_xor(pd, m); }
  if (c == 0) { a_s2[node] = ps; a_d2[node] = pd; }
}

// ---------------- GAT layer 2 aggregate + pooling atomics ----------------
// one wave per dst node; 16 output channels.
__global__ void gat2_agg_kernel(const int* __restrict__ rowptr, const int* __restrict__ csr_src,
                                const float* __restrict__ h2, const float* __restrict__ a_s2,
                                const float* __restrict__ a_d2, const float* __restrict__ b2,
                                const int* __restrict__ batch,
                                float* __restrict__ pooled, float* __restrict__ cntb, int n) {
  int dst = blockIdx.x;
  int lane = threadIdx.x;
  int beg = rowptr[dst], end = rowptr[dst + 1];
  int deg = end - beg;
  __shared__ float p_lds[64];
  __shared__ int s_lds[64];
  float M = -1e30f, S = 0.f, acc = 0.f;
  float adv = a_d2[dst];

  for (int base = 0; base < deg; base += 64) {
    int cnt = min(64, deg - base);
    float e = -1e30f; int s = 0;
    if (lane < cnt) {
      s = csr_src[beg + base + lane];
      float ev = a_s2[s] + adv;
      e = ev > 0.f ? ev : 0.2f * ev;
    }
    float cm = e;
    #pragma unroll
    for (int m = 1; m < 64; m <<= 1) cm = fmaxf(cm, __shfl_xor(cm, m));
    float newM = fmaxf(M, cm);
    float p = (lane < cnt) ? __expf(e - newM) : 0.f;
    float ss = p;
    #pragma unroll
    for (int m = 1; m < 64; m <<= 1) ss += __shfl_xor(ss, m);
    float sc = __expf(M - newM);
    S = S * sc + ss;
    M = newM;
    p_lds[lane] = p; s_lds[lane] = s;
    __syncthreads();
    if (lane < 16) {
      acc *= sc;
      for (int i = 0; i < cnt; ++i)
        acc += p_lds[i] * h2[(size_t)s_lds[i] * 16 + lane];
    }
    __syncthreads();
  }

  if (lane < 16) {
    float v = acc / (S + 1e-16f) + b2[lane];
    int g = batch[dst];
    atomicAdd(&pooled[g * 16 + lane], v);
    if (lane == 0) atomicAdd(&cntb[g], 1.f);
  }
}

// ---------------- final: mean + log_softmax ----------------
__global__ void final_kernel(const float* __restrict__ pooled, const float* __restrict__ cntb,
                             float* __restrict__ out, int G) {
  int g = threadIdx.x;
  if (g >= G) return;
  float c = fmaxf(cntb[g], 1.f);
  float v[16];
  float m = -1e30f;
  #pragma unroll
  for (int i = 0; i < 16; ++i) { v[i] = pooled[g * 16 + i] / c; m = fmaxf(m, v[i]); }
  float s = 0.f;
  #pragma unroll
  for (int i = 0; i < 16; ++i) s += __expf(v[i] - m);
  float ls = logf(s);
  #pragma unroll
  for (int i = 0; i < 16; ++i) out[g * 16 + i] = v[i] - m - ls;
}

// ---------------- launcher ----------------
extern "C" void kernel_launch(void* const* d_in, const int* in_sizes, int n_in,
                              void* d_out, int out_size, void* d_ws, size_t ws_size,
                              hipStream_t stream) {
  const float* x    = (const float*)d_in[0];
  const int*   eidx = (const int*)  d_in[1];
  const int*   batch= (const int*)  d_in[2];
  const float* W1   = (const float*)d_in[3];
  const float* as1w = (const float*)d_in[4];
  const float* ad1w = (const float*)d_in[5];
  const float* b1   = (const float*)d_in[6];
  const float* W2   = (const float*)d_in[7];
  const float* as2w = (const float*)d_in[8];
  const float* ad2w = (const float*)d_in[9];
  const float* b2   = (const float*)d_in[10];
  float* out = (float*)d_out;

  int N = in_sizes[0] / 128;
  int E = in_sizes[1] / 2;
  int G = out_size / 16;
  const int* esrc = eidx;
  const int* edst = eidx + E;

  char* p = (char*)d_ws;
  auto alloc = [&](size_t bytes) {
    char* r = p;
    p += (bytes + 255) & ~(size_t)255;
    return r;
  };
  float* h1   = (float*)alloc((size_t)N * 128 * 4);
  float* hmid = (float*)alloc((size_t)N * 128 * 4);
  float* h2   = (float*)alloc((size_t)N * 16 * 4);
  float* as1  = (float*)alloc((size_t)N * 8 * 4);
  float* ad1  = (float*)alloc((size_t)N * 8 * 4);
  float* as2  = (float*)alloc((size_t)N * 4);
  float* ad2  = (float*)alloc((size_t)N * 4);
  float* pooled = (float*)alloc((size_t)(G * 16 + G) * 4);
  float* cntb = pooled + G * 16;
  int* deg    = (int*)alloc((size_t)N * 4);
  int* rowptr = (int*)alloc((size_t)(N + 1) * 4);
  int* fillc  = (int*)alloc((size_t)N * 4);
  int* csr    = (int*)alloc((size_t)E * 4);
  int* csum   = (int*)alloc(1024 * 4);

  hipMemsetAsync(deg, 0, (size_t)N * 4, stream);
  hipMemsetAsync(fillc, 0, (size_t)N * 4, stream);
  hipMemsetAsync(pooled, 0, (size_t)(G * 16 + G) * 4, stream);

  int nchunks = (N + 1023) / 1024;
  deg_kernel<<<(E + 255) / 256, 256, 0, stream>>>(edst, deg, E);
  chunk_sum_kernel<<<nchunks, 1024, 0, stream>>>(deg, csum, N);
  scan_chunks_kernel<<<1, 1024, 0, stream>>>(csum, nchunks);
  scan_final_kernel<<<nchunks, 1024, 0, stream>>>(deg, csum, rowptr, N);
  fill_kernel<<<(E + 255) / 256, 256, 0, stream>>>(esrc, edst, rowptr, fillc, csr, E);

  gemm1_kernel<<<(N + 63) / 64, 256, 0, stream>>>(x, W1, h1, N);
  att1_kernel<<<(N + 3) / 4, 256, 0, stream>>>(h1, as1w, ad1w, as1, ad1, N);
  gat1_agg_kernel<<<N, 128, 0, stream>>>(rowptr, csr, h1, as1, ad1, b1, hmid, N);
  gemm2_att2_kernel<<<(N * 16 + 255) / 256, 256, 0, stream>>>(hmid, W2, as2w, ad2w, h2, as2, ad2, N);
  gat2_agg_kernel<<<N, 64, 0, stream>>>(rowptr, csr, h2, as2, ad2, b2, batch, pooled, cntb, N);
  final_kernel<<<1, (G + 63) / 64 * 64, 0, stream>>>(pooled, cntb, out, G);
}

// Round 2
// 605.117 us; speedup vs baseline: 2.3703x; 2.3703x over previous
//
#include <hip/hip_runtime.h>
#include <cstdint>
#include <cstddef>

// ---------------- CSR construction ----------------

__global__ void deg_kernel(const int* __restrict__ edst, int* __restrict__ deg, int E) {
  int i = blockIdx.x * 256 + threadIdx.x;
  if (i < E) atomicAdd(&deg[edst[i]], 1);
}

__global__ void chunk_sum_kernel(const int* __restrict__ deg, int* __restrict__ csum, int n) {
  __shared__ int wsum[16];
  int t = threadIdx.x;
  int i = blockIdx.x * 1024 + t;
  int v = (i < n) ? deg[i] : 0;
  for (int m = 1; m < 64; m <<= 1) v += __shfl_xor(v, m);
  if ((t & 63) == 0) wsum[t >> 6] = v;
  __syncthreads();
  if (t == 0) {
    int s = 0;
    for (int j = 0; j < 16; ++j) s += wsum[j];
    csum[blockIdx.x] = s;
  }
}

// single block: inclusive scan of chunk sums (nchunks <= 1024)
__global__ void scan_chunks_kernel(int* __restrict__ csum, int nchunks) {
  __shared__ int wsum[16];
  int t = threadIdx.x;
  int lane = t & 63, w = t >> 6;
  int x = (t < nchunks) ? csum[t] : 0;
  for (int off = 1; off < 64; off <<= 1) { int y = __shfl_up(x, off); if (lane >= off) x += y; }
  if (lane == 63) wsum[w] = x;
  __syncthreads();
  if (t < 16) {
    int s = wsum[t];
    for (int off = 1; off < 16; off <<= 1) { int y = __shfl_up(s, off); if (t >= off) s += y; }
    wsum[t] = s;
  }
  __syncthreads();
  if (w > 0) x += wsum[w - 1];
  if (t < nchunks) csum[t] = x;
}

__global__ void scan_final_kernel(const int* __restrict__ deg, const int* __restrict__ csum,
                                  int* __restrict__ rowptr, int n) {
  __shared__ int wsum[16];
  int t = threadIdx.x, b = blockIdx.x;
  int i = b * 1024 + t;
  int lane = t & 63, w = t >> 6;
  int x = (i < n) ? deg[i] : 0;
  for (int off = 1; off < 64; off <<= 1) { int y = __shfl_up(x, off); if (lane >= off) x += y; }
  if (lane == 63) wsum[w] = x;
  __syncthreads();
  if (t < 16) {
    int s = wsum[t];
    for (int off = 1; off < 16; off <<= 1) { int y = __shfl_up(s, off); if (t >= off) s += y; }
    wsum[t] = s;
  }
  __syncthreads();
  if (w > 0) x += wsum[w - 1];
  int off0 = (b > 0) ? csum[b - 1] : 0;
  if (i < n) rowptr[i + 1] = off0 + x;
  if (b == 0 && t == 0) rowptr[0] = 0;
}

__global__ void fill_kernel(const int* __restrict__ esrc, const int* __restrict__ edst,
                            const int* __restrict__ rowptr, int* __restrict__ fillc,
                            int* __restrict__ csr_src, int E) {
  int i = blockIdx.x * 256 + threadIdx.x;
  if (i < E) {
    int d = edst[i];
    int pos = atomicAdd(&fillc[d], 1);
    csr_src[rowptr[d] + pos] = esrc[i];
  }
}

// ---------------- GEMM1: h1 = x @ W1  (N x 128 @ 128 x 128) ----------------
__global__ void gemm1_kernel(const float* __restrict__ x, const float* __restrict__ W,
                             float* __restrict__ h1, int n) {
  __shared__ float wlds[128 * 128];
  int t = threadIdx.x;
  for (int i = t * 4; i < 128 * 128; i += 256 * 4)
    *(float4*)&wlds[i] = *(const float4*)&W[i];
  __syncthreads();
  int cg = t & 31, rg = t >> 5;   // 32 col groups x 8 row groups
  int c0 = cg * 4;
  int row0 = blockIdx.x * 64 + rg * 8;
  float acc[8][4] = {};
  const float* xr[8];
  #pragma unroll
  for (int i = 0; i < 8; ++i) {
    int r = row0 + i;
    xr[i] = x + (size_t)(r < n ? r : 0) * 128;
  }
  #pragma unroll 4
  for (int k = 0; k < 128; ++k) {
    float4 w4 = *(float4*)&wlds[k * 128 + c0];
    #pragma unroll
    for (int i = 0; i < 8; ++i) {
      float xv = xr[i][k];
      acc[i][0] += xv * w4.x; acc[i][1] += xv * w4.y;
      acc[i][2] += xv * w4.z; acc[i][3] += xv * w4.w;
    }
  }
  #pragma unroll
  for (int i = 0; i < 8; ++i) {
    int r = row0 + i;
    if (r < n) {
      float4 o = { acc[i][0], acc[i][1], acc[i][2], acc[i][3] };
      *(float4*)&h1[(size_t)r * 128 + c0] = o;
    }
  }
}

// ---------------- attention coefficients layer 1 ----------------
__global__ void att1_kernel(const float* __restrict__ h1, const float* __restrict__ asw,
                            const float* __restrict__ adw,
                            float* __restrict__ a_s, float* __restrict__ a_d, int n) {
  int node = blockIdx.x * 4 + (threadIdx.x >> 6);
  int lane = threadIdx.x & 63;
  if (node >= n) return;
  float v1 = h1[(size_t)node * 128 + lane];
  float v2 = h1[(size_t)node * 128 + 64 + lane];
  float ps1 = v1 * asw[lane],      pd1 = v1 * adw[lane];
  float ps2 = v2 * asw[64 + lane], pd2 = v2 * adw[64 + lane];
  #pragma unroll
  for (int m = 1; m < 16; m <<= 1) {
    ps1 += __shfl_xor(ps1, m); pd1 += __shfl_xor(pd1, m);
    ps2 += __shfl_xor(ps2, m); pd2 += __shfl_xor(pd2, m);
  }
  if ((lane & 15) == 0) {
    int h = lane >> 4;
    a_s[(size_t)node * 8 + h]     = ps1;
    a_s[(size_t)node * 8 + 4 + h] = ps2;
    a_d[(size_t)node * 8 + h]     = pd1;
    a_d[(size_t)node * 8 + 4 + h] = pd2;
  }
}

// ---------------- GAT layer 1 aggregate ----------------
__global__ void gat1_agg_kernel(const int* __restrict__ rowptr, const int* __restrict__ csr_src,
                                const float* __restrict__ h1,
                                const float* __restrict__ a_s, const float* __restrict__ a_d,
                                const float* __restrict__ b1, float* __restrict__ hmid, int n) {
  int dst = blockIdx.x;
  int t = threadIdx.x;
  int beg = rowptr[dst], end = rowptr[dst + 1];
  int deg = end - beg;

  __shared__ float e_lds[128][8];
  __shared__ int   src_lds[128];
  __shared__ float M[8], S[8], scale[8];
  if (t < 8) { M[t] = -1e30f; S[t] = 0.f; }

  float ad[8];
  #pragma unroll
  for (int h = 0; h < 8; ++h) ad[h] = a_d[(size_t)dst * 8 + h];

  float acc = 0.f;
  int hh = t >> 4;

  for (int base = 0; base < deg; base += 128) {
    int cnt = min(128, deg - base);
    if (t < cnt) {
      int s = csr_src[beg + base + t];
      src_lds[t] = s;
      const float4* ap = (const float4*)&a_s[(size_t)s * 8];
      float4 A0 = ap[0], A1 = ap[1];
      float ev[8] = { A0.x + ad[0], A0.y + ad[1], A0.z + ad[2], A0.w + ad[3],
                      A1.x + ad[4], A1.y + ad[5], A1.z + ad[6], A1.w + ad[7] };
      #pragma unroll
      for (int h = 0; h < 8; ++h) {
        float e = ev[h];
        e_lds[t][h] = e > 0.f ? e : 0.2f * e;
      }
    }
    __syncthreads();
    if (t < 8) {
      int h = t;
      float m = M[h], cm = m;
      for (int i = 0; i < cnt; ++i) cm = fmaxf(cm, e_lds[i][h]);
      float sc = __expf(m - cm);
      float s = S[h] * sc;
      for (int i = 0; i < cnt; ++i) { float p = __expf(e_lds[i][h] - cm); e_lds[i][h] = p; s += p; }
      M[h] = cm; S[h] = s; scale[h] = sc;
    }
    __syncthreads();
    acc *= scale[hh];
    for (int i = 0; i < cnt; ++i)
      acc += e_lds[i][hh] * h1[(size_t)src_lds[i] * 128 + t];
    __syncthreads();
  }

  float denom = S[hh] + 1e-16f;
  float v = acc / denom + b1[t];
  v = v > 0.f ? v : (__expf(v) - 1.f);   // ELU
  hmid[(size_t)dst * 128 + t] = v;
}

// ---------------- GEMM2 + att2 fused ----------------
__global__ void gemm2_att2_kernel(const float* __restrict__ hmid, const float* __restrict__ W2,
                                  const float* __restrict__ asw, const float* __restrict__ adw,
                                  float* __restrict__ h2, float* __restrict__ a_s2,
                                  float* __restrict__ a_d2, int n) {
  __shared__ float w[128 * 16];
  int t = threadIdx.x;
  for (int i = t; i < 128 * 16; i += 256) w[i] = W2[i];
  __syncthreads();
  int gid = blockIdx.x * 256 + t;
  int node = gid >> 4, c = gid & 15;
  if (node >= n) return;
  const float* row = &hmid[(size_t)node * 128];
  float acc = 0.f;
  #pragma unroll 4
  for (int k = 0; k < 128; ++k) acc += row[k] * w[k * 16 + c];
  h2[(size_t)node * 16 + c] = acc;
  float ps = acc * asw[c], pd = acc * adw[c];
  #pragma unroll
  for (int m = 1; m < 16; m <<= 1) { ps += __shfl_xor(ps, m); pd += __shfl_xor(pd, m); }
  if (c == 0) { a_s2[node] = ps; a_d2[node] = pd; }
}

// ---------------- GAT layer 2 aggregate + pooled atomics (16-lane group per dst) ----------------
// 256 threads = 16 groups of 16 lanes; group owns one dst; lane = output channel.
__global__ void gat2_agg_kernel(const int* __restrict__ rowptr, const int* __restrict__ csr_src,
                                const float* __restrict__ h2, const float* __restrict__ a_s2,
                                const float* __restrict__ a_d2, const float* __restrict__ b2,
                                const int* __restrict__ batch,
                                float* __restrict__ pooled, float* __restrict__ cntb,
                                int n, int G) {
  __shared__ float pooledL[17][16];
  __shared__ float cntL[17];
  int t = threadIdx.x;
  if (t < 17) cntL[t] = 0.f;
  for (int i = t; i < 17 * 16; i += 256) ((float*)pooledL)[i] = 0.f;
  __syncthreads();

  int grp = t >> 4, c = t & 15;
  int dst = blockIdx.x * 16 + grp;
  int gfirst = batch[blockIdx.x * 16];   // block base always < n (grid = ceil(n/16))

  if (dst < n) {
    int beg = rowptr[dst], end = rowptr[dst + 1];
    int deg = end - beg;
    float M = -1e30f, S = 0.f, acc = 0.f;
    float adv = a_d2[dst];

    for (int base = 0; base < deg; base += 16) {
      int cnt = min(16, deg - base);
      int s = 0; float e = -1e30f;
      if (c < cnt) {
        s = csr_src[beg + base + c];
        float ev = a_s2[s] + adv;
        e = ev > 0.f ? ev : 0.2f * ev;
      }
      float cm = e;
      #pragma unroll
      for (int m = 1; m < 16; m <<= 1) cm = fmaxf(cm, __shfl_xor(cm, m));
      float newM = fmaxf(M, cm);
      float p = (c < cnt) ? __expf(e - newM) : 0.f;
      float ss = p;
      #pragma unroll
      for (int m = 1; m < 16; m <<= 1) ss += __shfl_xor(ss, m);
      float sc = __expf(M - newM);
      S = S * sc + ss;
      M = newM;
      acc *= sc;
      #pragma unroll
      for (int i = 0; i < 16; ++i) {
        float pi = __shfl(p, i, 16);
        int   si = __shfl(s, i, 16);
        acc = fmaf(pi, h2[(size_t)si * 16 + c], acc);
      }
    }

    float v = acc / (S + 1e-16f) + b2[c];
    int g = batch[dst];
    int gi = g - gfirst;
    if (gi <= 16) {
      atomicAdd(&pooledL[gi][c], v);
      if (c == 0) atomicAdd(&cntL[gi], 1.f);
    } else {                                    // pathological graph-span fallback
      atomicAdd(&pooled[g * 16 + c], v);
      if (c == 0) atomicAdd(&cntb[g], 1.f);
    }
  }
  __syncthreads();

  int w = t >> 5, lane32 = t & 31;
  for (int gi = w; gi < 17; gi += 8) {
    if (cntL[gi] > 0.f) {
      int g = gfirst + gi;
      if (lane32 < 16) atomicAdd(&pooled[g * 16 + lane32], pooledL[gi][lane32]);
      else if (lane32 == 16) atomicAdd(&cntb[g], cntL[gi]);
    }
  }
}

// ---------------- final: mean + log_softmax ----------------
__global__ void final_kernel(const float* __restrict__ pooled, const float* __restrict__ cntb,
                             float* __restrict__ out, int G) {
  int g = threadIdx.x;
  if (g >= G) return;
  float c = fmaxf(cntb[g], 1.f);
  float v[16];
  float m = -1e30f;
  #pragma unroll
  for (int i = 0; i < 16; ++i) { v[i] = pooled[g * 16 + i] / c; m = fmaxf(m, v[i]); }
  float s = 0.f;
  #pragma unroll
  for (int i = 0; i < 16; ++i) s += __expf(v[i] - m);
  float ls = logf(s);
  #pragma unroll
  for (int i = 0; i < 16; ++i) out[g * 16 + i] = v[i] - m - ls;
}

// ---------------- launcher ----------------
extern "C" void kernel_launch(void* const* d_in, const int* in_sizes, int n_in,
                              void* d_out, int out_size, void* d_ws, size_t ws_size,
                              hipStream_t stream) {
  const float* x    = (const float*)d_in[0];
  const int*   eidx = (const int*)  d_in[1];
  const int*   batch= (const int*)  d_in[2];
  const float* W1   = (const float*)d_in[3];
  const float* as1w = (const float*)d_in[4];
  const float* ad1w = (const float*)d_in[5];
  const float* b1   = (const float*)d_in[6];
  const float* W2   = (const float*)d_in[7];
  const float* as2w = (const float*)d_in[8];
  const float* ad2w = (const float*)d_in[9];
  const float* b2   = (const float*)d_in[10];
  float* out = (float*)d_out;

  int N = in_sizes[0] / 128;
  int E = in_sizes[1] / 2;
  int G = out_size / 16;
  const int* esrc = eidx;
  const int* edst = eidx + E;

  char* p = (char*)d_ws;
  auto alloc = [&](size_t bytes) {
    char* r = p;
    p += (bytes + 255) & ~(size_t)255;
    return r;
  };
  float* h1   = (float*)alloc((size_t)N * 128 * 4);
  float* hmid = (float*)alloc((size_t)N * 128 * 4);
  float* h2   = (float*)alloc((size_t)N * 16 * 4);
  float* as1  = (float*)alloc((size_t)N * 8 * 4);
  float* ad1  = (float*)alloc((size_t)N * 8 * 4);
  float* as2  = (float*)alloc((size_t)N * 4);
  float* ad2  = (float*)alloc((size_t)N * 4);
  float* pooled = (float*)alloc((size_t)(G * 16 + G) * 4);
  float* cntb = pooled + G * 16;
  int* deg    = (int*)alloc((size_t)N * 4);
  int* rowptr = (int*)alloc((size_t)(N + 1) * 4);
  int* fillc  = (int*)alloc((size_t)N * 4);
  int* csr    = (int*)alloc((size_t)E * 4);
  int* csum   = (int*)alloc(1024 * 4);

  hipMemsetAsync(deg, 0, (size_t)N * 4, stream);
  hipMemsetAsync(fillc, 0, (size_t)N * 4, stream);
  hipMemsetAsync(pooled, 0, (size_t)(G * 16 + G) * 4, stream);

  int nchunks = (N + 1023) / 1024;
  deg_kernel<<<(E + 255) / 256, 256, 0, stream>>>(edst, deg, E);
  chunk_sum_kernel<<<nchunks, 1024, 0, stream>>>(deg, csum, N);
  scan_chunks_kernel<<<1, 1024, 0, stream>>>(csum, nchunks);
  scan_final_kernel<<<nchunks, 1024, 0, stream>>>(deg, csum, rowptr, N);
  fill_kernel<<<(E + 255) / 256, 256, 0, stream>>>(esrc, edst, rowptr, fillc, csr, E);

  gemm1_kernel<<<(N + 63) / 64, 256, 0, stream>>>(x, W1, h1, N);
  att1_kernel<<<(N + 3) / 4, 256, 0, stream>>>(h1, as1w, ad1w, as1, ad1, N);
  gat1_agg_kernel<<<N, 128, 0, stream>>>(rowptr, csr, h1, as1, ad1, b1, hmid, N);
  gemm2_att2_kernel<<<(N * 16 + 255) / 256, 256, 0, stream>>>(hmid, W2, as2w, ad2w, h2, as2, ad2, N);
  gat2_agg_kernel<<<(N + 15) / 16, 256, 0, stream>>>(rowptr, csr, h2, as2, ad2, b2, batch, pooled, cntb, N, G);
  final_kernel<<<1, (G + 63) / 64 * 64, 0, stream>>>(pooled, cntb, out, G);
}